// Round 1
// baseline (500.803 us; speedup 1.0000x reference)
//
#include <hip/hip_runtime.h>
#include <hip/hip_bf16.h>
#include <cstdint>
#include <cstddef>

// WaveKAN FFN: B=4 S=2048 D=1024 H=4096, M = B*S = 8192.
// layer1: h = mexhat((x-t1)/s1) @ wav_w1^T + silu(x) @ base_w1^T   [M,H]
// layer2: out = mexhat((h-t2)/s2) @ wav_w2^T + silu(h) @ base_w2^T [M,D]
// Strategy: concat the two branch-GEMMs along K (K1=2D=2048, K2=2H=8192),
// bf16 MFMA (16x16x32) with fp32 accumulate. Layer-2 activations fused into
// GEMM1 epilogue -> h never materialized.

typedef __bf16 bf16x8 __attribute__((ext_vector_type(8)));
typedef float  f32x4  __attribute__((ext_vector_type(4)));

#define MH_C 0.8673250705840776f   // 2/sqrt(3) * pi^-0.25

__device__ __forceinline__ float mexhat_z(float z) {
    float z2 = z * z;
    return MH_C * (1.0f - z2) * __expf(-0.5f * z2);
}
__device__ __forceinline__ float silu_f(float x) {
    return x / (1.0f + __expf(-x));
}
__device__ __forceinline__ unsigned short f2bf(float f) {
    union { __hip_bfloat16 b; unsigned short u; } cv;
    cv.b = __float2bfloat16(f);
    return cv.u;
}

// dst [N, 2*Kh] bf16 = concat(a, b) along K. All dims multiples of 4.
__global__ void cast_cat_kernel(const float* __restrict__ a, const float* __restrict__ b,
                                unsigned short* __restrict__ dst, int N, int Kh) {
    int idx4 = (blockIdx.x * 256 + threadIdx.x) * 4;
    int twoK = 2 * Kh;
    if ((long)idx4 >= (long)N * twoK) return;
    int n = idx4 / twoK;
    int k = idx4 - n * twoK;
    const float* src = (k < Kh) ? (a + (size_t)n * Kh + k)
                                : (b + (size_t)n * Kh + (k - Kh));
    float4 v = *(const float4*)src;
    ushort4 o;
    o.x = f2bf(v.x); o.y = f2bf(v.y); o.z = f2bf(v.z); o.w = f2bf(v.w);
    *(ushort4*)(dst + (size_t)n * twoK + k) = o;
}

// dst [M, 2*D] bf16: k<D -> mexhat((x-t)/s), else silu(x)
__global__ void act_cat_kernel(const float* __restrict__ x, const float* __restrict__ trans,
                               const float* __restrict__ scale,
                               unsigned short* __restrict__ dst, int M, int D) {
    int idx4 = (blockIdx.x * 256 + threadIdx.x) * 4;
    int twoD = 2 * D;
    if ((long)idx4 >= (long)M * twoD) return;
    int m = idx4 / twoD;
    int k = idx4 - m * twoD;
    float4 o;
    if (k < D) {
        float4 xv = *(const float4*)(x + (size_t)m * D + k);
        float4 t  = *(const float4*)(trans + k);
        float4 s  = *(const float4*)(scale + k);
        o.x = mexhat_z((xv.x - t.x) / s.x);
        o.y = mexhat_z((xv.y - t.y) / s.y);
        o.z = mexhat_z((xv.z - t.z) / s.z);
        o.w = mexhat_z((xv.w - t.w) / s.w);
    } else {
        int kk = k - D;
        float4 xv = *(const float4*)(x + (size_t)m * D + kk);
        o.x = silu_f(xv.x); o.y = silu_f(xv.y);
        o.z = silu_f(xv.z); o.w = silu_f(xv.w);
    }
    ushort4 u;
    u.x = f2bf(o.x); u.y = f2bf(o.y); u.z = f2bf(o.z); u.w = f2bf(o.w);
    *(ushort4*)(dst + (size_t)m * twoD + k) = u;
}

// C = A @ Bt^T.  A [M,K] bf16 row-major, Bt [N,K] bf16 row-major.
// 128x128 tile, BK=64, 256 threads = 4 waves in 2x2, each wave 64x64 via
// 4x4 mfma_f32_16x16x32_bf16. global_load_lds(16B) staging with XOR chunk
// swizzle applied on the GLOBAL source side (LDS dest must stay
// wave-uniform-base + lane*16). LDS chunk (row, j) holds global k-chunk
// j ^ (row&7)  ->  fragment ds_read_b128 is <=2-way bank aliased (free).
// EPI=0: store fp32 C[M,N].  EPI=1: epilogue computes layer-2 activations
// and writes A2 [M, 2N] bf16 (wav | silu).
template<int EPI>
__global__ __launch_bounds__(256)
void gemm_bt_kernel(const unsigned short* __restrict__ A,
                    const unsigned short* __restrict__ Bt,
                    float* __restrict__ C,
                    unsigned short* __restrict__ A2,
                    const float* __restrict__ trans,
                    const float* __restrict__ scale,
                    int N, int K) {
    __shared__ __align__(16) unsigned short sA[128 * 64];
    __shared__ __align__(16) unsigned short sB[128 * 64];

    const int tid  = threadIdx.x;
    const int lane = tid & 63;
    const int wv   = tid >> 6;
    const int wm   = wv >> 1;          // wave row 0..1 (64 rows each)
    const int wn   = wv & 1;           // wave col 0..1
    const int rowBase = blockIdx.y * 128;
    const int colBase = blockIdx.x * 128;

    f32x4 acc[4][4] = {};

    for (int k0 = 0; k0 < K; k0 += 64) {
        // ---- stage A,B tiles: 128 rows x 8 chunks(16B) each ----
        #pragma unroll
        for (int r = 0; r < 4; ++r) {
            int c  = r * 256 + wv * 64 + lane;          // LDS chunk id
            int m  = c >> 3;                            // tile row
            int gk = ((c & 7) ^ (m & 7)) * 8;           // swizzled k offset (elems)
            const unsigned short* gpA = A  + (size_t)(rowBase + m) * K + k0 + gk;
            const unsigned short* gpB = Bt + (size_t)(colBase + m) * K + k0 + gk;
            unsigned short* lpA = sA + (size_t)(r * 256 + wv * 64) * 8; // wave-uniform
            unsigned short* lpB = sB + (size_t)(r * 256 + wv * 64) * 8;
            __builtin_amdgcn_global_load_lds(
                (const __attribute__((address_space(1))) void*)gpA,
                (__attribute__((address_space(3))) void*)lpA, 16, 0, 0);
            __builtin_amdgcn_global_load_lds(
                (const __attribute__((address_space(1))) void*)gpB,
                (__attribute__((address_space(3))) void*)lpB, 16, 0, 0);
        }
        __syncthreads();

        // ---- compute: 2 k-chunks of 32, 4x4 MFMA tiles per wave ----
        #pragma unroll
        for (int kk = 0; kk < 2; ++kk) {
            const int kcb = kk * 4 + (lane >> 4);       // k-chunk 0..7
            bf16x8 af[4], bfr[4];
            #pragma unroll
            for (int i = 0; i < 4; ++i) {
                int m = wm * 64 + i * 16 + (lane & 15);
                af[i] = *(const bf16x8*)(sA + (size_t)(m * 8 + (kcb ^ (m & 7))) * 8);
            }
            #pragma unroll
            for (int j = 0; j < 4; ++j) {
                int n = wn * 64 + j * 16 + (lane & 15);
                bfr[j] = *(const bf16x8*)(sB + (size_t)(n * 8 + (kcb ^ (n & 7))) * 8);
            }
            #pragma unroll
            for (int i = 0; i < 4; ++i)
                #pragma unroll
                for (int j = 0; j < 4; ++j)
                    acc[i][j] = __builtin_amdgcn_mfma_f32_16x16x32_bf16(
                        af[i], bfr[j], acc[i][j], 0, 0, 0);
        }
        __syncthreads();
    }

    // ---- epilogue: D[row=(lane>>4)*4+r][col=lane&15] (m89-verified) ----
    const int quad = lane >> 4;
    #pragma unroll
    for (int i = 0; i < 4; ++i) {
        int row0 = rowBase + wm * 64 + i * 16 + quad * 4;
        #pragma unroll
        for (int j = 0; j < 4; ++j) {
            int col = colBase + wn * 64 + j * 16 + (lane & 15);
            if (EPI == 0) {
                #pragma unroll
                for (int r = 0; r < 4; ++r)
                    C[(size_t)(row0 + r) * N + col] = acc[i][j][r];
            } else {
                float t  = trans[col];
                float sc = scale[col];
                #pragma unroll
                for (int r = 0; r < 4; ++r) {
                    float h = acc[i][j][r];
                    float z = (h - t) / sc;
                    size_t base = (size_t)(row0 + r) * (size_t)(2 * N) + col;
                    A2[base]     = f2bf(mexhat_z(z));
                    A2[base + N] = f2bf(silu_f(h));
                }
            }
        }
    }
}

extern "C" void kernel_launch(void* const* d_in, const int* in_sizes, int n_in,
                              void* d_out, int out_size, void* d_ws, size_t ws_size,
                              hipStream_t stream) {
    (void)in_sizes; (void)n_in; (void)out_size; (void)ws_size;
    const float* x       = (const float*)d_in[0];
    const float* scale1  = (const float*)d_in[1];
    const float* trans1  = (const float*)d_in[2];
    const float* wav_w1  = (const float*)d_in[3];
    const float* base_w1 = (const float*)d_in[4];
    const float* scale2  = (const float*)d_in[5];
    const float* trans2  = (const float*)d_in[6];
    const float* wav_w2  = (const float*)d_in[7];
    const float* base_w2 = (const float*)d_in[8];
    float* out = (float*)d_out;

    const int M = 8192, D = 1024, H = 4096;

    // workspace layout (bytes): W1c 16M | W2c 16M | A1 32M | A2 128M = 192 MiB
    unsigned short* W1c = (unsigned short*)d_ws;                 // [H, 2D]
    unsigned short* W2c = W1c + (size_t)H * 2 * D;               // [D, 2H]
    unsigned short* A1  = W2c + (size_t)D * 2 * H;               // [M, 2D]
    unsigned short* A2  = A1  + (size_t)M * 2 * D;               // [M, 2H]

    // weights -> bf16 concat
    {
        int total = H * 2 * D;   // 8.4M
        cast_cat_kernel<<<total / 4 / 256, 256, 0, stream>>>(wav_w1, base_w1, W1c, H, D);
        total = D * 2 * H;
        cast_cat_kernel<<<total / 4 / 256, 256, 0, stream>>>(wav_w2, base_w2, W2c, D, H);
    }
    // layer-1 activations
    {
        int total = M * 2 * D;   // 16.8M
        act_cat_kernel<<<total / 4 / 256, 256, 0, stream>>>(x, trans1, scale1, A1, M, D);
    }
    // GEMM1: [M,2D] @ [H,2D]^T -> fused layer-2 activations -> A2 [M,2H]
    {
        dim3 grid(H / 128, M / 128);   // (32, 64)
        gemm_bt_kernel<1><<<grid, 256, 0, stream>>>(A1, W1c, nullptr, A2,
                                                    trans2, scale2, H, 2 * D);
    }
    // GEMM2: [M,2H] @ [D,2H]^T -> out fp32 [M,D]
    {
        dim3 grid(D / 128, M / 128);   // (8, 64)
        gemm_bt_kernel<0><<<grid, 256, 0, stream>>>(A2, W2c, out, nullptr,
                                                    nullptr, nullptr, D, 2 * H);
    }
}